// Round 1
// baseline (185.952 us; speedup 1.0000x reference)
//
#include <hip/hip_runtime.h>
#include <math.h>

// Shapes (compile-time)
#define BB 16
#define LL 28
#define RR 64
#define DD 512
#define KK (RR * DD)   // 32768

// ---------------------------------------------------------------------------
// Kernel 1: G[b, r*D + d] = sum_l logits[b,l,r] * arg_embeddings[b,l,d]
// grid = B*R = 1024 blocks, block = 512 threads (thread = d)
// logits reads are block-uniform (scalar); arg slice per b is 57KB (L1/L2 hit)
// ---------------------------------------------------------------------------
__global__ void __launch_bounds__(512) kernel_g(
    const float* __restrict__ logits,   // [B,L,R]
    const float* __restrict__ arg,      // [B,L,D]
    float* __restrict__ G)              // [B, K]
{
    const int b = blockIdx.x >> 6;   // / 64
    const int r = blockIdx.x & 63;
    const int d = threadIdx.x;
    float acc = 0.f;
#pragma unroll
    for (int l = 0; l < LL; ++l) {
        const float lg = logits[(b * LL + l) * RR + r];      // uniform
        acc = fmaf(lg, arg[(b * LL + l) * DD + d], acc);
    }
    // index = b*K + r*D + d
    G[(size_t)blockIdx.x * DD + d] = acc;
}

// ---------------------------------------------------------------------------
// Kernel 2 (fused): blocks [0,256): split-K role GEMM chunks;
//                   blocks [256,512): evt transform chunks.
// block = 256 threads, each thread owns 2 consecutive e (float2 W loads).
// Results accumulate via float atomics into 64KB L2-resident buffers.
// ---------------------------------------------------------------------------
__global__ void __launch_bounds__(256) kernel_bc(
    const float* __restrict__ WRT,      // [R,D,D] -> flat [K, D]
    const float* __restrict__ WTT,      // [E,D,D]
    const float* __restrict__ evt_emb,  // [B,1,D]
    const int*   __restrict__ evt_type, // [B]
    const float* __restrict__ G,        // [B,K]
    float* __restrict__ div_acc,        // [B,D]
    float* __restrict__ evt_acc)        // [B,D]
{
    const int blk = blockIdx.x;
    const int tid = threadIdx.x;
    const int e   = tid * 2;

    if (blk < 256) {
        // role-transition split-K: chunk of 128 k values
        const int k0 = blk * 128;
        float acc[BB][2];
#pragma unroll
        for (int b = 0; b < BB; ++b) { acc[b][0] = 0.f; acc[b][1] = 0.f; }

#pragma unroll 4
        for (int kk = 0; kk < 128; ++kk) {
            const int k = k0 + kk;
            const float2 w = *(const float2*)(WRT + (size_t)k * DD + e);
#pragma unroll
            for (int b = 0; b < BB; ++b) {
                const float g = G[b * KK + k];   // wave-uniform -> s_load
                acc[b][0] = fmaf(g, w.x, acc[b][0]);
                acc[b][1] = fmaf(g, w.y, acc[b][1]);
            }
        }
#pragma unroll
        for (int b = 0; b < BB; ++b) {
            atomicAdd(&div_acc[b * DD + e],     acc[b][0]);
            atomicAdd(&div_acc[b * DD + e + 1], acc[b][1]);
        }
    } else {
        // evt transform: evt_trans[b,e] = sum_d emb[b,d] * WTT[t_b, d, e]
        const int blk2 = blk - 256;
        const int b  = blk2 >> 4;        // 16 b
        const int c  = blk2 & 15;        // 16 d-chunks of 32
        const int d0 = c * 32;
        const int t  = evt_type[b];
        const float* Wt = WTT + (size_t)t * DD * DD;
        float a0 = 0.f, a1 = 0.f;
#pragma unroll 4
        for (int dd = 0; dd < 32; ++dd) {
            const int d = d0 + dd;
            const float em = evt_emb[b * DD + d];            // uniform
            const float2 w = *(const float2*)(Wt + (size_t)d * DD + e);
            a0 = fmaf(em, w.x, a0);
            a1 = fmaf(em, w.y, a1);
        }
        atomicAdd(&evt_acc[b * DD + e],     a0);
        atomicAdd(&evt_acc[b * DD + e + 1], a1);
    }
}

// ---------------------------------------------------------------------------
// Kernel 3: graph = (div + evt)/2; h = relu(graph@w1 + b1); out = sigmoid(h@w2+b2)
// grid = B blocks, block = 64 threads (one wave), thread = hidden unit j
// ---------------------------------------------------------------------------
__global__ void __launch_bounds__(64) kernel_mlp(
    const float* __restrict__ div_acc,  // [B,D]
    const float* __restrict__ evt_acc,  // [B,D]
    const float* __restrict__ w1,       // [D,64]
    const float* __restrict__ b1,       // [64]
    const float* __restrict__ w2,       // [64,1]
    const float* __restrict__ b2,       // [1]
    float* __restrict__ out)            // [B,1]
{
    const int b = blockIdx.x;
    const int j = threadIdx.x;
    float h = b1[j];
#pragma unroll 8
    for (int d = 0; d < DD; ++d) {
        const float g = (div_acc[b * DD + d] + evt_acc[b * DD + d]) * 0.5f; // uniform
        h = fmaf(g, w1[d * 64 + j], h);
    }
    h = fmaxf(h, 0.f);
    float v = h * w2[j];
#pragma unroll
    for (int off = 32; off > 0; off >>= 1) v += __shfl_down(v, off, 64);
    if (j == 0) out[b] = 1.f / (1.f + expf(-(v + b2[0])));
}

// ---------------------------------------------------------------------------
extern "C" void kernel_launch(void* const* d_in, const int* in_sizes, int n_in,
                              void* d_out, int out_size, void* d_ws, size_t ws_size,
                              hipStream_t stream) {
    const float* logits   = (const float*)d_in[0];
    const float* evt_emb  = (const float*)d_in[1];
    const float* arg_emb  = (const float*)d_in[2];
    // d_in[3] arg_padding_num: cancels algebraically (x*c summed then /c), unused
    const int*   evt_type = (const int*)d_in[4];
    const float* WRT      = (const float*)d_in[5];
    const float* WTT      = (const float*)d_in[6];
    const float* w1       = (const float*)d_in[7];
    const float* b1       = (const float*)d_in[8];
    const float* w2       = (const float*)d_in[9];
    const float* b2       = (const float*)d_in[10];
    float* out = (float*)d_out;

    float* G       = (float*)d_ws;           // B*K floats = 2 MB
    float* div_acc = G + BB * KK;            // B*D = 8192 floats
    float* evt_acc = div_acc + BB * DD;      // B*D = 8192 floats

    hipMemsetAsync(div_acc, 0, 2 * BB * DD * sizeof(float), stream);

    hipLaunchKernelGGL(kernel_g, dim3(BB * RR), dim3(DD), 0, stream,
                       logits, arg_emb, G);
    hipLaunchKernelGGL(kernel_bc, dim3(512), dim3(256), 0, stream,
                       WRT, WTT, evt_emb, evt_type, G, div_acc, evt_acc);
    hipLaunchKernelGGL(kernel_mlp, dim3(BB), dim3(64), 0, stream,
                       div_acc, evt_acc, w1, b1, w2, b2, out);
}

// Round 2
// 166.749 us; speedup vs baseline: 1.1152x; 1.1152x over previous
//
#include <hip/hip_runtime.h>
#include <math.h>

// Shapes (compile-time)
#define BB 16
#define LL 28
#define RR 64
#define DD 512
#define KK (RR * DD)        // 32768
#define NROLE 512           // role blocks; each covers k-chunk of 64 = (r, 64-wide d range)
#define NEVT 128            // evt blocks; each covers (b, 64-wide d range)

// ---------------------------------------------------------------------------
// Kernel A (fused):
//  blocks [0, NROLE): role split-K. Phase 1 computes the G slice
//    G[b, r, d0..d0+63] = sum_l logits[b,l,r]*arg[b,l,d] into 4 KB LDS.
//    Phase 2 streams WRT[r, d0..d0+63, :] with float4 loads, G via uniform
//    ds_read_b128 broadcast. Partial [16][512] written to workspace (no atomics).
//  blocks [NROLE, NROLE+NEVT): evt transform, float4 WTT loads, atomics into
//    evt_acc (131K lane-atomics total — trivial).
// ---------------------------------------------------------------------------
__global__ void __launch_bounds__(256) kernel_a(
    const float* __restrict__ logits,   // [B,L,R]
    const float* __restrict__ arg,      // [B,L,D]
    const float* __restrict__ WRT,      // [R,D,D]
    const float* __restrict__ WTT,      // [E,D,D]
    const float* __restrict__ evt_emb,  // [B,1,D]
    const int*   __restrict__ evt_type, // [B]
    float* __restrict__ part,           // [NROLE][16][512]
    float* __restrict__ evt_acc)        // [B,D]
{
    __shared__ float smem[8192];        // 32 KB (4 KB G region reused for combine)
    const int t = threadIdx.x;

    if (blockIdx.x >= NROLE) {
        // ---------------- evt transform ----------------
        const int blk = blockIdx.x - NROLE;
        const int b  = blk >> 3;
        const int d0 = (blk & 7) * 64;
        const int ty = evt_type[b];
        const float* Wt = WTT + (size_t)ty * DD * DD;
        const int e4 = t & 127;         // float4 column index
        const int s  = t >> 7;          // 2 d-streams
        float4 a = {0.f, 0.f, 0.f, 0.f};
#pragma unroll 4
        for (int dd = s; dd < 64; dd += 2) {
            const int d = d0 + dd;
            const float em = evt_emb[b * DD + d];                  // uniform
            const float4 w = ((const float4*)(Wt + (size_t)d * DD))[e4];
            a.x = fmaf(em, w.x, a.x);
            a.y = fmaf(em, w.y, a.y);
            a.z = fmaf(em, w.z, a.z);
            a.w = fmaf(em, w.w, a.w);
        }
        atomicAdd(&evt_acc[b * DD + e4 * 4 + 0], a.x);
        atomicAdd(&evt_acc[b * DD + e4 * 4 + 1], a.y);
        atomicAdd(&evt_acc[b * DD + e4 * 4 + 2], a.z);
        atomicAdd(&evt_acc[b * DD + e4 * 4 + 3], a.w);
        return;
    }

    // ---------------- role split-K ----------------
    const int blk = blockIdx.x;
    const int r  = blk >> 3;
    const int d0 = (blk & 7) * 64;

    // Phase 1: G_lds[dd][b] for dd in [0,64), b in [0,16). Layout [64][16] floats.
    {
        const int dl = t & 63;          // d-local (wave-contiguous -> coalesced arg)
        const int b4 = t >> 6;          // 4 b-groups (wave-uniform)
        float g0 = 0.f, g1 = 0.f, g2 = 0.f, g3 = 0.f;
        const int d = d0 + dl;
#pragma unroll
        for (int l = 0; l < LL; ++l) {
            const int b0 = b4 * 4;
            const float a0 = arg[((b0 + 0) * LL + l) * DD + d];
            const float a1 = arg[((b0 + 1) * LL + l) * DD + d];
            const float a2 = arg[((b0 + 2) * LL + l) * DD + d];
            const float a3 = arg[((b0 + 3) * LL + l) * DD + d];
            g0 = fmaf(logits[((b0 + 0) * LL + l) * RR + r], a0, g0);
            g1 = fmaf(logits[((b0 + 1) * LL + l) * RR + r], a1, g1);
            g2 = fmaf(logits[((b0 + 2) * LL + l) * RR + r], a2, g2);
            g3 = fmaf(logits[((b0 + 3) * LL + l) * RR + r], a3, g3);
        }
        ((float4*)smem)[dl * 4 + b4] = make_float4(g0, g1, g2, g3);
    }
    __syncthreads();

    // Phase 2: acc[b][0..3] over k-chunk; thread = (e-float4, k-stream)
    const int e4 = t & 127;
    const int ks = t >> 7;
    const float4* Wp = (const float4*)(WRT + ((size_t)(r * DD + d0)) * DD);
    const float4* Gl = (const float4*)smem;   // [64][4] float4
    float4 acc[16];
#pragma unroll
    for (int b = 0; b < 16; ++b) acc[b] = make_float4(0.f, 0.f, 0.f, 0.f);

#pragma unroll 2
    for (int kk = ks; kk < 64; kk += 2) {
        const float4 w = Wp[(size_t)kk * 128 + e4];   // 16 B/lane, 1 KB/wave
        float4 g[4];
        g[0] = Gl[kk * 4 + 0];   // uniform broadcast reads
        g[1] = Gl[kk * 4 + 1];
        g[2] = Gl[kk * 4 + 2];
        g[3] = Gl[kk * 4 + 3];
        const float* gs = (const float*)g;
#pragma unroll
        for (int b = 0; b < 16; ++b) {
            acc[b].x = fmaf(gs[b], w.x, acc[b].x);
            acc[b].y = fmaf(gs[b], w.y, acc[b].y);
            acc[b].z = fmaf(gs[b], w.z, acc[b].z);
            acc[b].w = fmaf(gs[b], w.w, acc[b].w);
        }
    }
    __syncthreads();   // G region no longer needed

    // Combine the 2 k-streams via LDS, then store partial (no atomics).
    if (ks == 1) {
        float4* red = (float4*)smem;
#pragma unroll
        for (int b = 0; b < 16; ++b) red[(t - 128) * 16 + b] = acc[b];
    }
    __syncthreads();
    if (ks == 0) {
        const float4* red = (const float4*)smem;
        float4* po = (float4*)part + (size_t)blk * 2048;   // [16][128] float4
#pragma unroll
        for (int b = 0; b < 16; ++b) {
            float4 o = acc[b];
            const float4 q = red[t * 16 + b];
            o.x += q.x; o.y += q.y; o.z += q.z; o.w += q.w;
            po[b * 128 + e4] = o;
        }
    }
}

// ---------------------------------------------------------------------------
// Reduce: div[o] = sum_p part[p][o], o in [0, 16*512). 32 p-segments of 16,
// 8 o-chunks of 1024 floats. 262K lane-atomics into zeroed div_acc.
// ---------------------------------------------------------------------------
__global__ void __launch_bounds__(256) kernel_reduce(
    const float* __restrict__ part,     // [NROLE][8192]
    float* __restrict__ div_acc)        // [8192]
{
    const int ps = blockIdx.x & 31;     // p-segment (16 partials)
    const int oc = blockIdx.x >> 5;     // o-chunk (1024 floats = 256 float4)
    const int t  = threadIdx.x;
    const int o4 = oc * 256 + t;        // float4 index into [0,2048)
    const float4* p4 = (const float4*)part;
    float4 s = {0.f, 0.f, 0.f, 0.f};
#pragma unroll
    for (int i = 0; i < 16; ++i) {
        const int p = ps * 16 + i;
        const float4 v = p4[(size_t)p * 2048 + o4];
        s.x += v.x; s.y += v.y; s.z += v.z; s.w += v.w;
    }
    atomicAdd(&div_acc[o4 * 4 + 0], s.x);
    atomicAdd(&div_acc[o4 * 4 + 1], s.y);
    atomicAdd(&div_acc[o4 * 4 + 2], s.z);
    atomicAdd(&div_acc[o4 * 4 + 3], s.w);
}

// ---------------------------------------------------------------------------
// MLP: graph=(div+evt)/2 ; h=relu(graph@w1+b1) ; out=sigmoid(h@w2+b2)
// 16 blocks x 256 threads: thread = (hidden j, d-quarter). LDS+shuffle reduce.
// ---------------------------------------------------------------------------
__global__ void __launch_bounds__(256) kernel_mlp(
    const float* __restrict__ div_acc,  // [B,D]
    const float* __restrict__ evt_acc,  // [B,D]
    const float* __restrict__ w1,       // [D,64]
    const float* __restrict__ b1,       // [64]
    const float* __restrict__ w2,       // [64,1]
    const float* __restrict__ b2,       // [1]
    float* __restrict__ out)            // [B,1]
{
    __shared__ float hred[256];
    const int b  = blockIdx.x;
    const int t  = threadIdx.x;
    const int j  = t & 63;
    const int dq = t >> 6;
    float hp = 0.f;
#pragma unroll 8
    for (int i = 0; i < 128; ++i) {
        const int d = dq * 128 + i;
        const float g = (div_acc[b * DD + d] + evt_acc[b * DD + d]) * 0.5f; // uniform
        hp = fmaf(g, w1[d * 64 + j], hp);
    }
    hred[t] = hp;
    __syncthreads();
    if (t < 64) {
        float h = b1[j] + hred[j] + hred[64 + j] + hred[128 + j] + hred[192 + j];
        h = fmaxf(h, 0.f);
        float v = h * w2[j];
#pragma unroll
        for (int off = 32; off > 0; off >>= 1) v += __shfl_down(v, off, 64);
        if (j == 0) out[b] = 1.f / (1.f + expf(-(v + b2[0])));
    }
}

// ---------------------------------------------------------------------------
extern "C" void kernel_launch(void* const* d_in, const int* in_sizes, int n_in,
                              void* d_out, int out_size, void* d_ws, size_t ws_size,
                              hipStream_t stream) {
    const float* logits   = (const float*)d_in[0];
    const float* evt_emb  = (const float*)d_in[1];
    const float* arg_emb  = (const float*)d_in[2];
    // d_in[3] arg_padding_num cancels algebraically; unused
    const int*   evt_type = (const int*)d_in[4];
    const float* WRT      = (const float*)d_in[5];
    const float* WTT      = (const float*)d_in[6];
    const float* w1       = (const float*)d_in[7];
    const float* b1       = (const float*)d_in[8];
    const float* w2       = (const float*)d_in[9];
    const float* b2       = (const float*)d_in[10];
    float* out = (float*)d_out;

    float* part    = (float*)d_ws;              // NROLE*8192 floats = 16.78 MB
    float* div_acc = part + (size_t)NROLE * 8192;
    float* evt_acc = div_acc + BB * DD;

    hipMemsetAsync(div_acc, 0, 2 * BB * DD * sizeof(float), stream);

    hipLaunchKernelGGL(kernel_a, dim3(NROLE + NEVT), dim3(256), 0, stream,
                       logits, arg_emb, WRT, WTT, evt_emb, evt_type, part, evt_acc);
    hipLaunchKernelGGL(kernel_reduce, dim3(256), dim3(256), 0, stream,
                       part, div_acc);
    hipLaunchKernelGGL(kernel_mlp, dim3(BB), dim3(256), 0, stream,
                       div_acc, evt_acc, w1, b1, w2, b2, out);
}

// Round 3
// 162.169 us; speedup vs baseline: 1.1467x; 1.0282x over previous
//
#include <hip/hip_runtime.h>
#include <math.h>

// Shapes (compile-time)
#define BB 16
#define LL 28
#define RR 64
#define DD 512
#define KK (RR * DD)        // 32768
#define NROLE 512           // role blocks; k-chunk 64 = (r, 64-wide d range)
#define NEVT 128            // evt blocks; (b, 64-wide d range)

// ---------------------------------------------------------------------------
// Kernel A (fused):
//  blocks [0, NROLE): role split-K.
//    Prefetch first 8 WRT float4s -> phase 1 builds G slice in 4 KB LDS
//    (vectorized float4 arg loads) -> phase 2 streams 131 KB of WRT with an
//    8-deep register-double-buffered pipeline (128 B/lane in flight),
//    G via uniform ds_read_b128 broadcast. Partial [16][512] to workspace.
//  blocks [NROLE, NROLE+NEVT): evt transform, 8-deep batched float4 WTT loads,
//    atomics into evt_acc.
// ---------------------------------------------------------------------------
__global__ void __launch_bounds__(256) kernel_a(
    const float* __restrict__ logits,   // [B,L,R]
    const float* __restrict__ arg,      // [B,L,D]
    const float* __restrict__ WRT,      // [R,D,D]
    const float* __restrict__ WTT,      // [E,D,D]
    const float* __restrict__ evt_emb,  // [B,1,D]
    const int*   __restrict__ evt_type, // [B]
    float* __restrict__ part,           // [NROLE][16][512]
    float* __restrict__ evt_acc)        // [B,D]
{
    __shared__ float smem[8192];        // 32 KB: [0,1024) = G slice; combine reuses
    const int t = threadIdx.x;

    if (blockIdx.x >= NROLE) {
        // ---------------- evt transform ----------------
        const int blk = blockIdx.x - NROLE;
        const int b  = blk >> 3;
        const int d0 = (blk & 7) * 64;
        const int ty = evt_type[b];
        const float* Wt = WTT + (size_t)ty * DD * DD;
        const int e4 = t & 127;
        const int s  = t >> 7;          // 2 d-streams
        float4 a = {0.f, 0.f, 0.f, 0.f};
#pragma unroll
        for (int db = 0; db < 64; db += 16) {
            float  em[8];
            float4 w[8];
#pragma unroll
            for (int i = 0; i < 8; ++i) {
                const int d = d0 + db + s + 2 * i;
                em[i] = evt_emb[b * DD + d];                       // uniform
                w[i]  = ((const float4*)(Wt + (size_t)d * DD))[e4];
            }
#pragma unroll
            for (int i = 0; i < 8; ++i) {
                a.x = fmaf(em[i], w[i].x, a.x);
                a.y = fmaf(em[i], w[i].y, a.y);
                a.z = fmaf(em[i], w[i].z, a.z);
                a.w = fmaf(em[i], w[i].w, a.w);
            }
        }
        atomicAdd(&evt_acc[b * DD + e4 * 4 + 0], a.x);
        atomicAdd(&evt_acc[b * DD + e4 * 4 + 1], a.y);
        atomicAdd(&evt_acc[b * DD + e4 * 4 + 2], a.z);
        atomicAdd(&evt_acc[b * DD + e4 * 4 + 3], a.w);
        return;
    }

    // ---------------- role split-K ----------------
    const int blk = blockIdx.x;
    const int r  = blk >> 3;
    const int d0 = (blk & 7) * 64;

    const int e4 = t & 127;             // float4 column in [0,128)
    const int ks = t >> 7;              // 2 k-streams
    const float4* Wp = (const float4*)(WRT + ((size_t)(r * DD + d0)) * DD);

    // Prefetch first WRT batch BEFORE phase 1 so the HBM stream starts now.
    float4 w[8];
#pragma unroll
    for (int i = 0; i < 8; ++i)
        w[i] = Wp[(size_t)(ks + 2 * i) * 128 + e4];

    // Phase 1: G_lds[dd][b], dd in [0,64), b in [0,16). Layout [64][16] floats.
    {
        const int d4 = t & 15;          // float4 d-group (coalesced arg)
        const int b  = t >> 4;          // batch index
        const float4* ap = (const float4*)(arg + d0) + d4;
        float4 g = {0.f, 0.f, 0.f, 0.f};
#pragma unroll
        for (int l = 0; l < LL; ++l) {
            const float lg = logits[(b * LL + l) * RR + r];
            const float4 av = ap[(size_t)(b * LL + l) * 128];
            g.x = fmaf(lg, av.x, g.x);
            g.y = fmaf(lg, av.y, g.y);
            g.z = fmaf(lg, av.z, g.z);
            g.w = fmaf(lg, av.w, g.w);
        }
        smem[(4 * d4 + 0) * 16 + b] = g.x;
        smem[(4 * d4 + 1) * 16 + b] = g.y;
        smem[(4 * d4 + 2) * 16 + b] = g.z;
        smem[(4 * d4 + 3) * 16 + b] = g.w;
    }
    __syncthreads();

    // Phase 2: software-pipelined K-loop, 8 float4 loads in flight per lane.
    const float4* Gl = (const float4*)smem;   // [64][4] float4
    float4 acc[16];
#pragma unroll
    for (int b = 0; b < 16; ++b) acc[b] = make_float4(0.f, 0.f, 0.f, 0.f);

#pragma unroll
    for (int kb = 0; kb < 64; kb += 16) {
        float4 wn[8];
        if (kb + 16 < 64) {
#pragma unroll
            for (int i = 0; i < 8; ++i)
                wn[i] = Wp[(size_t)(kb + 16 + ks + 2 * i) * 128 + e4];
        }
#pragma unroll
        for (int i = 0; i < 8; ++i) {
            const int kk = kb + ks + 2 * i;
            float4 g[4];
            g[0] = Gl[kk * 4 + 0];      // uniform broadcast reads
            g[1] = Gl[kk * 4 + 1];
            g[2] = Gl[kk * 4 + 2];
            g[3] = Gl[kk * 4 + 3];
            const float* gs = (const float*)g;
#pragma unroll
            for (int b = 0; b < 16; ++b) {
                acc[b].x = fmaf(gs[b], w[i].x, acc[b].x);
                acc[b].y = fmaf(gs[b], w[i].y, acc[b].y);
                acc[b].z = fmaf(gs[b], w[i].z, acc[b].z);
                acc[b].w = fmaf(gs[b], w[i].w, acc[b].w);
            }
        }
#pragma unroll
        for (int i = 0; i < 8; ++i) w[i] = wn[i];
    }
    __syncthreads();   // G region no longer needed

    // Combine the 2 k-streams via LDS, then store partial (no atomics).
    if (ks == 1) {
        float4* red = (float4*)smem;
#pragma unroll
        for (int b = 0; b < 16; ++b) red[(t - 128) * 16 + b] = acc[b];
    }
    __syncthreads();
    if (ks == 0) {
        const float4* red = (const float4*)smem;
        float4* po = (float4*)part + (size_t)blk * 2048;   // [16][128] float4
#pragma unroll
        for (int b = 0; b < 16; ++b) {
            float4 o = acc[b];
            const float4 q = red[t * 16 + b];
            o.x += q.x; o.y += q.y; o.z += q.z; o.w += q.w;
            po[b * 128 + e4] = o;
        }
    }
}

// ---------------------------------------------------------------------------
// Reduce: div[o] = sum_p part[p][o]. 32 p-segments x 8 o-chunks; atomics into
// zeroed div_acc (262K lane-atomics, L2-resident).
// ---------------------------------------------------------------------------
__global__ void __launch_bounds__(256) kernel_reduce(
    const float* __restrict__ part,     // [NROLE][8192]
    float* __restrict__ div_acc)        // [8192]
{
    const int ps = blockIdx.x & 31;
    const int oc = blockIdx.x >> 5;
    const int t  = threadIdx.x;
    const int o4 = oc * 256 + t;
    const float4* p4 = (const float4*)part;
    float4 s = {0.f, 0.f, 0.f, 0.f};
#pragma unroll
    for (int i = 0; i < 16; ++i) {
        const int p = ps * 16 + i;
        const float4 v = p4[(size_t)p * 2048 + o4];
        s.x += v.x; s.y += v.y; s.z += v.z; s.w += v.w;
    }
    atomicAdd(&div_acc[o4 * 4 + 0], s.x);
    atomicAdd(&div_acc[o4 * 4 + 1], s.y);
    atomicAdd(&div_acc[o4 * 4 + 2], s.z);
    atomicAdd(&div_acc[o4 * 4 + 3], s.w);
}

// ---------------------------------------------------------------------------
// MLP: graph=(div+evt)/2 ; h=relu(graph@w1+b1) ; out=sigmoid(h@w2+b2)
// ---------------------------------------------------------------------------
__global__ void __launch_bounds__(256) kernel_mlp(
    const float* __restrict__ div_acc,  // [B,D]
    const float* __restrict__ evt_acc,  // [B,D]
    const float* __restrict__ w1,       // [D,64]
    const float* __restrict__ b1,       // [64]
    const float* __restrict__ w2,       // [64,1]
    const float* __restrict__ b2,       // [1]
    float* __restrict__ out)            // [B,1]
{
    __shared__ float hred[256];
    const int b  = blockIdx.x;
    const int t  = threadIdx.x;
    const int j  = t & 63;
    const int dq = t >> 6;
    float hp = 0.f;
#pragma unroll 8
    for (int i = 0; i < 128; ++i) {
        const int d = dq * 128 + i;
        const float g = (div_acc[b * DD + d] + evt_acc[b * DD + d]) * 0.5f;
        hp = fmaf(g, w1[d * 64 + j], hp);
    }
    hred[t] = hp;
    __syncthreads();
    if (t < 64) {
        float h = b1[j] + hred[j] + hred[64 + j] + hred[128 + j] + hred[192 + j];
        h = fmaxf(h, 0.f);
        float v = h * w2[j];
#pragma unroll
        for (int off = 32; off > 0; off >>= 1) v += __shfl_down(v, off, 64);
        if (j == 0) out[b] = 1.f / (1.f + expf(-(v + b2[0])));
    }
}

// ---------------------------------------------------------------------------
extern "C" void kernel_launch(void* const* d_in, const int* in_sizes, int n_in,
                              void* d_out, int out_size, void* d_ws, size_t ws_size,
                              hipStream_t stream) {
    const float* logits   = (const float*)d_in[0];
    const float* evt_emb  = (const float*)d_in[1];
    const float* arg_emb  = (const float*)d_in[2];
    // d_in[3] arg_padding_num cancels algebraically; unused
    const int*   evt_type = (const int*)d_in[4];
    const float* WRT      = (const float*)d_in[5];
    const float* WTT      = (const float*)d_in[6];
    const float* w1       = (const float*)d_in[7];
    const float* b1       = (const float*)d_in[8];
    const float* w2       = (const float*)d_in[9];
    const float* b2       = (const float*)d_in[10];
    float* out = (float*)d_out;

    float* part    = (float*)d_ws;              // NROLE*8192 floats = 16.78 MB
    float* div_acc = part + (size_t)NROLE * 8192;
    float* evt_acc = div_acc + BB * DD;

    hipMemsetAsync(div_acc, 0, 2 * BB * DD * sizeof(float), stream);

    hipLaunchKernelGGL(kernel_a, dim3(NROLE + NEVT), dim3(256), 0, stream,
                       logits, arg_emb, WRT, WTT, evt_emb, evt_type, part, evt_acc);
    hipLaunchKernelGGL(kernel_reduce, dim3(256), dim3(256), 0, stream,
                       part, div_acc);
    hipLaunchKernelGGL(kernel_mlp, dim3(BB), dim3(256), 0, stream,
                       div_acc, evt_acc, w1, b1, w2, b2, out);
}